// Round 1
// baseline (86.146 us; speedup 1.0000x reference)
//
#include <hip/hip_runtime.h>
#include <math.h>

// BalNoisedTopK: loss = mean_i relu(1 + mean_j kth_max(s_i + Z_ij, excl y_i) - s_{i,y_i})
// s: (n, d) f32, y: (n,) i32, Z: (n, d, m) f32, out: scalar f32.
// K=5, m=8, eps=1.0 are compile-time constants per the reference.

#define KTOP 5
#define MSAMP 8
#define TPB 256

// v is sorted ascending: v[0] = current K-th largest (min of the top-K set).
__device__ __forceinline__ void topk_insert(float (&v)[KTOP], float x) {
    if (x > v[0]) {
        v[0] = x;
        // single bubble pass restores sortedness (only v[0] is out of place)
        #pragma unroll
        for (int q = 0; q < KTOP - 1; ++q) {
            float a = fminf(v[q], v[q + 1]);
            float b = fmaxf(v[q], v[q + 1]);
            v[q] = a; v[q + 1] = b;
        }
    }
}

__global__ __launch_bounds__(TPB) void topk_partial(
    const float* __restrict__ s, const int* __restrict__ y,
    const float* __restrict__ Z, float* __restrict__ cand,
    int d, int nchunks, int chunk)
{
    const int blk = blockIdx.x;
    const int i = blk / nchunks;
    const int c = blk % nchunks;
    const int e0 = c * chunk;
    const int e1 = min(e0 + chunk, d);
    const int yi = y[i];

    const float* __restrict__ srow = s + (size_t)i * d;
    const float* __restrict__ zrow = Z + (size_t)i * d * MSAMP;

    float v[MSAMP][KTOP];
    #pragma unroll
    for (int j = 0; j < MSAMP; ++j)
        #pragma unroll
        for (int q = 0; q < KTOP; ++q) v[j][q] = -INFINITY;

    for (int e = e0 + (int)threadIdx.x; e < e1; e += TPB) {
        float sv = srow[e];
        const float4* zp = (const float4*)(zrow + (size_t)e * MSAMP);
        float4 z0 = zp[0];
        float4 z1 = zp[1];
        if (e == yi) continue;   // excluded class: s_ny = -inf, never in top-k
        topk_insert(v[0], sv + z0.x);
        topk_insert(v[1], sv + z0.y);
        topk_insert(v[2], sv + z0.z);
        topk_insert(v[3], sv + z0.w);
        topk_insert(v[4], sv + z1.x);
        topk_insert(v[5], sv + z1.y);
        topk_insert(v[6], sv + z1.z);
        topk_insert(v[7], sv + z1.w);
    }

    // Intra-wave butterfly merge: every lane ends with the wave's merged top-5.
    #pragma unroll
    for (int off = 32; off >= 1; off >>= 1) {
        #pragma unroll
        for (int j = 0; j < MSAMP; ++j) {
            float o[KTOP];
            #pragma unroll
            for (int q = 0; q < KTOP; ++q) o[q] = __shfl_xor(v[j][q], off, 64);
            // insert largest first so later (smaller) values early-out
            #pragma unroll
            for (int q = KTOP - 1; q >= 0; --q) topk_insert(v[j], o[q]);
        }
    }

    __shared__ float lds[TPB / 64][MSAMP][KTOP];
    const int wave = threadIdx.x >> 6;
    const int lane = threadIdx.x & 63;
    if (lane == 0) {
        #pragma unroll
        for (int j = 0; j < MSAMP; ++j)
            #pragma unroll
            for (int q = 0; q < KTOP; ++q) lds[wave][j][q] = v[j][q];
    }
    __syncthreads();

    if (threadIdx.x < MSAMP) {
        const int j = threadIdx.x;
        float f[KTOP];
        #pragma unroll
        for (int q = 0; q < KTOP; ++q) f[q] = lds[0][j][q];
        #pragma unroll
        for (int w = 1; w < TPB / 64; ++w)
            #pragma unroll
            for (int q = KTOP - 1; q >= 0; --q) topk_insert(f, lds[w][j][q]);
        float* out = cand + (((size_t)i * nchunks + c) * MSAMP + j) * KTOP;
        #pragma unroll
        for (int q = 0; q < KTOP; ++q) out[q] = f[q];
    }
}

// One block; thread t = i*MSAMP + j. Merges per-chunk candidates, averages the
// kth max over samples, computes the hinge loss, reduces the batch mean.
__global__ __launch_bounds__(512) void finalize(
    const float* __restrict__ s, const int* __restrict__ y,
    const float* __restrict__ cand, float* __restrict__ out,
    int n, int d, int nchunks)
{
    const int t = threadIdx.x;
    const int i = t >> 3;
    const int j = t & 7;

    __shared__ float lsum[64];
    if (t < 64) lsum[t] = 0.0f;
    __syncthreads();

    if (i < n) {
        float v[KTOP];
        #pragma unroll
        for (int q = 0; q < KTOP; ++q) v[q] = -INFINITY;
        for (int c = 0; c < nchunks; ++c) {
            const float* p = cand + (((size_t)i * nchunks + c) * MSAMP + j) * KTOP;
            #pragma unroll
            for (int q = KTOP - 1; q >= 0; --q) topk_insert(v, p[q]);
        }
        float kth = v[0];                    // exact 5th-largest for (i,j)
        kth += __shfl_xor(kth, 1, 64);
        kth += __shfl_xor(kth, 2, 64);
        kth += __shfl_xor(kth, 4, 64);
        if (j == 0) {
            float kth_smooth = kth * (1.0f / (float)MSAMP);
            float sy = s[(size_t)i * d + y[i]];
            lsum[i] = fmaxf(1.0f + kth_smooth - sy, 0.0f);
        }
    }
    __syncthreads();

    if (t < 64) {
        float x = lsum[t];
        #pragma unroll
        for (int off = 32; off >= 1; off >>= 1) x += __shfl_xor(x, off, 64);
        if (t == 0) out[0] = x / (float)n;
    }
}

extern "C" void kernel_launch(void* const* d_in, const int* in_sizes, int n_in,
                              void* d_out, int out_size, void* d_ws, size_t ws_size,
                              hipStream_t stream) {
    const float* s = (const float*)d_in[0];
    const int*   y = (const int*)d_in[1];
    const float* Z = (const float*)d_in[2];
    float* out = (float*)d_out;

    const int n = in_sizes[1];
    const int d = in_sizes[0] / n;

    int nchunks = 16;
    while (nchunks > 1 &&
           (size_t)n * nchunks * MSAMP * KTOP * sizeof(float) > ws_size) {
        nchunks >>= 1;
    }
    const int chunk = (d + nchunks - 1) / nchunks;
    float* cand = (float*)d_ws;

    hipLaunchKernelGGL(topk_partial, dim3(n * nchunks), dim3(TPB), 0, stream,
                       s, y, Z, cand, d, nchunks, chunk);
    hipLaunchKernelGGL(finalize, dim3(1), dim3(n * MSAMP), 0, stream,
                       s, y, cand, out, n, d, nchunks);
}

// Round 2
// 54.343 us; speedup vs baseline: 1.5852x; 1.5852x over previous
//
#include <hip/hip_runtime.h>
#include <math.h>

// BalNoisedTopK: loss = mean_i relu(1 + mean_j kth_max(s_i + Z_ij, excl y_i) - s_{i,y_i})
// s: (n, d) f32, y: (n,) i32, Z: (n, d, m) f32 (m innermost), out: scalar f32.
// K=5, m=8, eps=1.0 compile-time constants per the reference.

#define KTOP 5
#define MSAMP 8
#define TPB 256
#define NCHUNKS_MAX 32

// v sorted ascending; v[0] = current 5th-largest. Branchless insert:
// new v[q] = median(x, v[q], v[q+1]) == clamp(x, v[q], v[q+1]) since v sorted.
__device__ __forceinline__ void topk_insert_bl(float (&v)[KTOP], float x) {
    float n0 = __builtin_amdgcn_fmed3f(x, v[0], v[1]);
    float n1 = __builtin_amdgcn_fmed3f(x, v[1], v[2]);
    float n2 = __builtin_amdgcn_fmed3f(x, v[2], v[3]);
    float n3 = __builtin_amdgcn_fmed3f(x, v[3], v[4]);
    float n4 = fmaxf(v[4], x);
    v[0] = n0; v[1] = n1; v[2] = n2; v[3] = n3; v[4] = n4;
}

__global__ __launch_bounds__(TPB) void topk_partial(
    const float* __restrict__ s, const int* __restrict__ y,
    const float* __restrict__ Z, float* __restrict__ cand,
    int d, int nchunks, int chunk)
{
    const int i = blockIdx.x / nchunks;
    const int c = blockIdx.x % nchunks;
    const int e0 = c * chunk;
    const int e1 = min(e0 + chunk, d);
    const int yi = y[i];

    const int t = threadIdx.x;
    const int j = t & 7;          // sample owned by this lane
    const int eofs = t >> 3;      // 0..31: element offset within block stride

    const float* __restrict__ srow = s + (size_t)i * d;
    const float* __restrict__ zrow = Z + (size_t)i * d * MSAMP;

    float v[KTOP];
    #pragma unroll
    for (int q = 0; q < KTOP; ++q) v[q] = -INFINITY;

    // Block covers 32 elements x 8 samples per iteration; the wave's 64 Z
    // loads are 256B contiguous. Single basic block -> pipelined loads.
    #pragma unroll 4
    for (int e = e0 + eofs; e < e1; e += 32) {
        float sv = srow[e];
        float z  = zrow[(size_t)e * MSAMP + j];
        float x  = (e == yi) ? -INFINITY : (sv + z);
        topk_insert_bl(v, x);
    }

    // Butterfly merge across the 8 lanes that share sample j (xor 8/16/32
    // preserves t&7). Afterwards lanes 0..7 of each wave hold per-sample top5.
    #pragma unroll
    for (int off = 8; off <= 32; off <<= 1) {
        float o[KTOP];
        #pragma unroll
        for (int q = 0; q < KTOP; ++q) o[q] = __shfl_xor(v[q], off, 64);
        #pragma unroll
        for (int q = 0; q < KTOP; ++q) topk_insert_bl(v, o[q]);
    }

    __shared__ float lds[TPB / 64][MSAMP][KTOP];
    const int wave = t >> 6;
    const int lane = t & 63;
    if (lane < MSAMP) {
        #pragma unroll
        for (int q = 0; q < KTOP; ++q) lds[wave][lane][q] = v[q];
    }
    __syncthreads();

    if (t < MSAMP) {
        float f[KTOP];
        #pragma unroll
        for (int q = 0; q < KTOP; ++q) f[q] = lds[0][t][q];
        #pragma unroll
        for (int w = 1; w < TPB / 64; ++w)
            #pragma unroll
            for (int q = 0; q < KTOP; ++q) topk_insert_bl(f, lds[w][t][q]);
        float* out = cand + (((size_t)i * nchunks + c) * MSAMP + t) * KTOP;
        #pragma unroll
        for (int q = 0; q < KTOP; ++q) out[q] = f[q];
    }
}

// One block; thread t = i*MSAMP + j. Merges per-chunk candidates, averages the
// kth max over samples, computes the hinge loss, reduces the batch mean.
__global__ __launch_bounds__(512) void finalize(
    const float* __restrict__ s, const int* __restrict__ y,
    const float* __restrict__ cand, float* __restrict__ out,
    int n, int d, int nchunks)
{
    const int t = threadIdx.x;
    const int i = t >> 3;
    const int j = t & 7;

    __shared__ float lsum[64];
    if (t < 64) lsum[t] = 0.0f;
    __syncthreads();

    if (i < n) {
        float v[KTOP];
        #pragma unroll
        for (int q = 0; q < KTOP; ++q) v[q] = -INFINITY;
        for (int c = 0; c < nchunks; ++c) {
            const float* p = cand + (((size_t)i * nchunks + c) * MSAMP + j) * KTOP;
            #pragma unroll
            for (int q = 0; q < KTOP; ++q) topk_insert_bl(v, p[q]);
        }
        float kth = v[0];                    // exact 5th-largest for (i,j)
        kth += __shfl_xor(kth, 1, 64);
        kth += __shfl_xor(kth, 2, 64);
        kth += __shfl_xor(kth, 4, 64);
        if (j == 0) {
            float kth_smooth = kth * (1.0f / (float)MSAMP);
            float sy = s[(size_t)i * d + y[i]];
            lsum[i] = fmaxf(1.0f + kth_smooth - sy, 0.0f);
        }
    }
    __syncthreads();

    if (t < 64) {
        float x = lsum[t];
        #pragma unroll
        for (int off = 32; off >= 1; off >>= 1) x += __shfl_xor(x, off, 64);
        if (t == 0) out[0] = x / (float)n;
    }
}

extern "C" void kernel_launch(void* const* d_in, const int* in_sizes, int n_in,
                              void* d_out, int out_size, void* d_ws, size_t ws_size,
                              hipStream_t stream) {
    const float* s = (const float*)d_in[0];
    const int*   y = (const int*)d_in[1];
    const float* Z = (const float*)d_in[2];
    float* out = (float*)d_out;

    const int n = in_sizes[1];
    const int d = in_sizes[0] / n;

    int nchunks = NCHUNKS_MAX;
    while (nchunks > 1 &&
           (size_t)n * nchunks * MSAMP * KTOP * sizeof(float) > ws_size) {
        nchunks >>= 1;
    }
    const int chunk = (d + nchunks - 1) / nchunks;
    float* cand = (float*)d_ws;

    hipLaunchKernelGGL(topk_partial, dim3(n * nchunks), dim3(TPB), 0, stream,
                       s, y, Z, cand, d, nchunks, chunk);
    hipLaunchKernelGGL(finalize, dim3(1), dim3(n * MSAMP), 0, stream,
                       s, y, cand, out, n, d, nchunks);
}

// Round 3
// 44.434 us; speedup vs baseline: 1.9387x; 1.2230x over previous
//
#include <hip/hip_runtime.h>
#include <math.h>

// BalNoisedTopK: loss = mean_i relu(1 + mean_j kth_max(s_i + Z_ij, excl y_i) - s_{i,y_i})
// s: (n, d) f32, y: (n,) i32, Z: (n, d, m) f32 (m innermost), out: scalar f32.
// K=5, m=8, eps=1.0 compile-time constants per the reference.

#define KTOP 5
#define MSAMP 8
#define TPB 256
#define NCHUNKS 32

// v sorted ascending; v[0] = current 5th-largest. Branchless insert:
// new v[q] = median(x, v[q], v[q+1]) == clamp(x, v[q], v[q+1]) since v sorted.
__device__ __forceinline__ void topk_insert_bl(float (&v)[KTOP], float x) {
    float n0 = __builtin_amdgcn_fmed3f(x, v[0], v[1]);
    float n1 = __builtin_amdgcn_fmed3f(x, v[1], v[2]);
    float n2 = __builtin_amdgcn_fmed3f(x, v[2], v[3]);
    float n3 = __builtin_amdgcn_fmed3f(x, v[3], v[4]);
    float n4 = fmaxf(v[4], x);
    v[0] = n0; v[1] = n1; v[2] = n2; v[3] = n3; v[4] = n4;
}

__global__ __launch_bounds__(TPB) void topk_partial(
    const float* __restrict__ s, const int* __restrict__ y,
    const float* __restrict__ Z, float* __restrict__ cand,
    int d, int nchunks, int chunk)
{
    const int i = blockIdx.x / nchunks;
    const int c = blockIdx.x % nchunks;
    const int e0 = c * chunk;                 // chunk is 32-aligned
    const int e1 = min(e0 + chunk, d);
    const int yi = y[i];

    const int t = threadIdx.x;
    const int j = t & 7;          // sample owned by this lane
    const int eofs = t >> 3;      // 0..31: element offset within block stride

    const float* __restrict__ srow = s + (size_t)i * d;
    const float* __restrict__ zrow = Z + (size_t)i * d * MSAMP;

    float v[KTOP];
    #pragma unroll
    for (int q = 0; q < KTOP; ++q) v[q] = -INFINITY;

    // Block covers 32 elements x 8 samples per iteration; the wave's 64 Z
    // loads are one aligned 256B segment. Branchless body -> pipelined loads.
    #pragma unroll 8
    for (int e = e0 + eofs; e < e1; e += 32) {
        float sv = srow[e];
        float z  = zrow[(size_t)e * MSAMP + j];
        float x  = (e == yi) ? -INFINITY : (sv + z);
        topk_insert_bl(v, x);
    }

    // Butterfly merge across the 8 lanes that share sample j (xor 8/16/32
    // preserves t&7). Afterwards every lane holds its wave's per-sample top5.
    #pragma unroll
    for (int off = 8; off <= 32; off <<= 1) {
        float o[KTOP];
        #pragma unroll
        for (int q = 0; q < KTOP; ++q) o[q] = __shfl_xor(v[q], off, 64);
        #pragma unroll
        for (int q = 0; q < KTOP; ++q) topk_insert_bl(v, o[q]);
    }

    __shared__ float lds[TPB / 64][MSAMP][KTOP];
    const int wave = t >> 6;
    const int lane = t & 63;
    if (lane < MSAMP) {
        #pragma unroll
        for (int q = 0; q < KTOP; ++q) lds[wave][lane][q] = v[q];
    }
    __syncthreads();

    if (t < MSAMP) {
        float f[KTOP];
        #pragma unroll
        for (int q = 0; q < KTOP; ++q) f[q] = lds[0][t][q];
        #pragma unroll
        for (int w = 1; w < TPB / 64; ++w)
            #pragma unroll
            for (int q = 0; q < KTOP; ++q) topk_insert_bl(f, lds[w][t][q]);
        float* out = cand + (((size_t)i * nchunks + c) * MSAMP + t) * KTOP;
        #pragma unroll
        for (int q = 0; q < KTOP; ++q) out[q] = f[q];
    }
}

// One block per row i; 256 threads: thread t -> chunk c = t>>3, sample j = t&7.
// Merges chunk candidates (butterfly over c within wave, LDS across waves),
// averages kth over samples, writes the row hinge loss.
__global__ __launch_bounds__(TPB) void row_loss(
    const float* __restrict__ s, const int* __restrict__ y,
    const float* __restrict__ cand, float* __restrict__ rloss,
    int d, int nchunks)
{
    const int i = blockIdx.x;
    const int t = threadIdx.x;
    const int j = t & 7;
    const int wave = t >> 6;
    const int lane = t & 63;

    float v[KTOP];
    #pragma unroll
    for (int q = 0; q < KTOP; ++q) v[q] = -INFINITY;

    for (int c = t >> 3; c < nchunks; c += TPB / MSAMP) {
        const float* p = cand + (((size_t)i * nchunks + c) * MSAMP + j) * KTOP;
        #pragma unroll
        for (int q = 0; q < KTOP; ++q) topk_insert_bl(v, p[q]);
    }

    // Merge across the 8 chunk-slots sharing sample j inside this wave.
    #pragma unroll
    for (int off = 8; off <= 32; off <<= 1) {
        float o[KTOP];
        #pragma unroll
        for (int q = 0; q < KTOP; ++q) o[q] = __shfl_xor(v[q], off, 64);
        #pragma unroll
        for (int q = 0; q < KTOP; ++q) topk_insert_bl(v, o[q]);
    }

    __shared__ float lds[TPB / 64][MSAMP][KTOP];
    __shared__ float kth_j[MSAMP];
    if (lane < MSAMP) {
        #pragma unroll
        for (int q = 0; q < KTOP; ++q) lds[wave][lane][q] = v[q];
    }
    __syncthreads();

    if (t < MSAMP) {
        float f[KTOP];
        #pragma unroll
        for (int q = 0; q < KTOP; ++q) f[q] = lds[0][t][q];
        #pragma unroll
        for (int w = 1; w < TPB / 64; ++w)
            #pragma unroll
            for (int q = 0; q < KTOP; ++q) topk_insert_bl(f, lds[w][t][q]);
        kth_j[t] = f[0];                 // exact 5th-largest for (i, j=t)
    }
    __syncthreads();

    if (t == 0) {
        float sum = 0.0f;
        #pragma unroll
        for (int jj = 0; jj < MSAMP; ++jj) sum += kth_j[jj];
        float kth_smooth = sum * (1.0f / (float)MSAMP);
        float sy = s[(size_t)i * d + y[i]];
        rloss[i] = fmaxf(1.0f + kth_smooth - sy, 0.0f);
    }
}

__global__ __launch_bounds__(64) void mean_loss(
    const float* __restrict__ rloss, float* __restrict__ out, int n)
{
    const int t = threadIdx.x;
    float x = (t < n) ? rloss[t] : 0.0f;
    #pragma unroll
    for (int off = 32; off >= 1; off >>= 1) x += __shfl_xor(x, off, 64);
    if (t == 0) out[0] = x / (float)n;
}

extern "C" void kernel_launch(void* const* d_in, const int* in_sizes, int n_in,
                              void* d_out, int out_size, void* d_ws, size_t ws_size,
                              hipStream_t stream) {
    const float* s = (const float*)d_in[0];
    const int*   y = (const int*)d_in[1];
    const float* Z = (const float*)d_in[2];
    float* out = (float*)d_out;

    const int n = in_sizes[1];
    const int d = in_sizes[0] / n;

    int nchunks = NCHUNKS;
    while (nchunks > 1 &&
           (size_t)n * nchunks * MSAMP * KTOP * sizeof(float) + n * sizeof(float)
               > ws_size) {
        nchunks >>= 1;
    }
    int chunk = (d + nchunks - 1) / nchunks;
    chunk = (chunk + 31) & ~31;           // 32-aligned -> aligned Z segments
    float* cand  = (float*)d_ws;
    float* rloss = cand + (size_t)n * nchunks * MSAMP * KTOP;

    hipLaunchKernelGGL(topk_partial, dim3(n * nchunks), dim3(TPB), 0, stream,
                       s, y, Z, cand, d, nchunks, chunk);
    hipLaunchKernelGGL(row_loss, dim3(n), dim3(TPB), 0, stream,
                       s, y, cand, rloss, d, nchunks);
    hipLaunchKernelGGL(mean_loss, dim3(1), dim3(64), 0, stream,
                       rloss, out, n);
}

// Round 4
// 44.405 us; speedup vs baseline: 1.9400x; 1.0006x over previous
//
#include <hip/hip_runtime.h>
#include <math.h>

// BalNoisedTopK: loss = mean_i relu(1 + mean_j kth_max(s_i + Z_ij, excl y_i) - s_{i,y_i})
// s: (n, d) f32, y: (n,) i32, Z: (n, d, m) f32 (m innermost), out: scalar f32.
// K=5, m=8, eps=1.0 compile-time constants per the reference.

#define KTOP 5
#define MSAMP 8
#define TPB 256
#define NCHUNKS 32

// v sorted ascending; v[0] = current 5th-largest. Branchless insert:
// new v[q] = median(x, v[q], v[q+1]) == clamp(x, v[q], v[q+1]) since v sorted.
__device__ __forceinline__ void topk_insert_bl(float (&v)[KTOP], float x) {
    float n0 = __builtin_amdgcn_fmed3f(x, v[0], v[1]);
    float n1 = __builtin_amdgcn_fmed3f(x, v[1], v[2]);
    float n2 = __builtin_amdgcn_fmed3f(x, v[2], v[3]);
    float n3 = __builtin_amdgcn_fmed3f(x, v[3], v[4]);
    float n4 = fmaxf(v[4], x);
    v[0] = n0; v[1] = n1; v[2] = n2; v[3] = n3; v[4] = n4;
}

__global__ __launch_bounds__(TPB) void topk_partial(
    const float* __restrict__ s, const int* __restrict__ y,
    const float* __restrict__ Z, float* __restrict__ cand,
    int d, int nchunks, int chunk)
{
    const int i = blockIdx.x / nchunks;
    const int c = blockIdx.x % nchunks;
    const int e0 = c * chunk;                 // chunk is 32-aligned
    const int e1 = min(e0 + chunk, d);
    const int yi = y[i];

    const int t = threadIdx.x;
    const int j = t & 7;          // sample owned by this lane
    const int eofs = t >> 3;      // 0..31: element offset within block stride

    const float* __restrict__ srow = s + (size_t)i * d;
    const float* __restrict__ zrow = Z + (size_t)i * d * MSAMP;

    float v[KTOP];
    #pragma unroll
    for (int q = 0; q < KTOP; ++q) v[q] = -INFINITY;

    // Block covers 32 elements x 8 samples per iteration; the wave's 64 Z
    // loads are one aligned 256B segment. Branchless body -> pipelined loads.
    #pragma unroll 8
    for (int e = e0 + eofs; e < e1; e += 32) {
        float sv = srow[e];
        float z  = zrow[(size_t)e * MSAMP + j];
        float x  = (e == yi) ? -INFINITY : (sv + z);
        topk_insert_bl(v, x);
    }

    // Butterfly merge across the 8 lanes that share sample j (xor 8/16/32
    // preserves t&7). Afterwards every lane holds its wave's per-sample top5.
    #pragma unroll
    for (int off = 8; off <= 32; off <<= 1) {
        float o[KTOP];
        #pragma unroll
        for (int q = 0; q < KTOP; ++q) o[q] = __shfl_xor(v[q], off, 64);
        #pragma unroll
        for (int q = 0; q < KTOP; ++q) topk_insert_bl(v, o[q]);
    }

    __shared__ float lds[TPB / 64][MSAMP][KTOP];
    const int wave = t >> 6;
    const int lane = t & 63;
    if (lane < MSAMP) {
        #pragma unroll
        for (int q = 0; q < KTOP; ++q) lds[wave][lane][q] = v[q];
    }
    __syncthreads();

    if (t < MSAMP) {
        float f[KTOP];
        #pragma unroll
        for (int q = 0; q < KTOP; ++q) f[q] = lds[0][t][q];
        #pragma unroll
        for (int w = 1; w < TPB / 64; ++w)
            #pragma unroll
            for (int q = 0; q < KTOP; ++q) topk_insert_bl(f, lds[w][t][q]);
        float* out = cand + (((size_t)i * nchunks + c) * MSAMP + t) * KTOP;
        #pragma unroll
        for (int q = 0; q < KTOP; ++q) out[q] = f[q];
    }
}

// One block per row i; 256 threads: thread t -> chunk c = t>>3, sample j = t&7.
// Merges chunk candidates (butterfly over c within wave, LDS across waves),
// averages kth over samples, writes the row hinge loss.
__global__ __launch_bounds__(TPB) void row_loss(
    const float* __restrict__ s, const int* __restrict__ y,
    const float* __restrict__ cand, float* __restrict__ rloss,
    int d, int nchunks)
{
    const int i = blockIdx.x;
    const int t = threadIdx.x;
    const int j = t & 7;
    const int wave = t >> 6;
    const int lane = t & 63;

    float v[KTOP];
    #pragma unroll
    for (int q = 0; q < KTOP; ++q) v[q] = -INFINITY;

    for (int c = t >> 3; c < nchunks; c += TPB / MSAMP) {
        const float* p = cand + (((size_t)i * nchunks + c) * MSAMP + j) * KTOP;
        #pragma unroll
        for (int q = 0; q < KTOP; ++q) topk_insert_bl(v, p[q]);
    }

    // Merge across the 8 chunk-slots sharing sample j inside this wave.
    #pragma unroll
    for (int off = 8; off <= 32; off <<= 1) {
        float o[KTOP];
        #pragma unroll
        for (int q = 0; q < KTOP; ++q) o[q] = __shfl_xor(v[q], off, 64);
        #pragma unroll
        for (int q = 0; q < KTOP; ++q) topk_insert_bl(v, o[q]);
    }

    __shared__ float lds[TPB / 64][MSAMP][KTOP];
    __shared__ float kth_j[MSAMP];
    if (lane < MSAMP) {
        #pragma unroll
        for (int q = 0; q < KTOP; ++q) lds[wave][lane][q] = v[q];
    }
    __syncthreads();

    if (t < MSAMP) {
        float f[KTOP];
        #pragma unroll
        for (int q = 0; q < KTOP; ++q) f[q] = lds[0][t][q];
        #pragma unroll
        for (int w = 1; w < TPB / 64; ++w)
            #pragma unroll
            for (int q = 0; q < KTOP; ++q) topk_insert_bl(f, lds[w][t][q]);
        kth_j[t] = f[0];                 // exact 5th-largest for (i, j=t)
    }
    __syncthreads();

    if (t == 0) {
        float sum = 0.0f;
        #pragma unroll
        for (int jj = 0; jj < MSAMP; ++jj) sum += kth_j[jj];
        float kth_smooth = sum * (1.0f / (float)MSAMP);
        float sy = s[(size_t)i * d + y[i]];
        rloss[i] = fmaxf(1.0f + kth_smooth - sy, 0.0f);
    }
}

__global__ __launch_bounds__(64) void mean_loss(
    const float* __restrict__ rloss, float* __restrict__ out, int n)
{
    const int t = threadIdx.x;
    float x = (t < n) ? rloss[t] : 0.0f;
    #pragma unroll
    for (int off = 32; off >= 1; off >>= 1) x += __shfl_xor(x, off, 64);
    if (t == 0) out[0] = x / (float)n;
}

extern "C" void kernel_launch(void* const* d_in, const int* in_sizes, int n_in,
                              void* d_out, int out_size, void* d_ws, size_t ws_size,
                              hipStream_t stream) {
    const float* s = (const float*)d_in[0];
    const int*   y = (const int*)d_in[1];
    const float* Z = (const float*)d_in[2];
    float* out = (float*)d_out;

    const int n = in_sizes[1];
    const int d = in_sizes[0] / n;

    int nchunks = NCHUNKS;
    while (nchunks > 1 &&
           (size_t)n * nchunks * MSAMP * KTOP * sizeof(float) + n * sizeof(float)
               > ws_size) {
        nchunks >>= 1;
    }
    int chunk = (d + nchunks - 1) / nchunks;
    chunk = (chunk + 31) & ~31;           // 32-aligned -> aligned Z segments
    float* cand  = (float*)d_ws;
    float* rloss = cand + (size_t)n * nchunks * MSAMP * KTOP;

    hipLaunchKernelGGL(topk_partial, dim3(n * nchunks), dim3(TPB), 0, stream,
                       s, y, Z, cand, d, nchunks, chunk);
    hipLaunchKernelGGL(row_loss, dim3(n), dim3(TPB), 0, stream,
                       s, y, cand, rloss, d, nchunks);
    hipLaunchKernelGGL(mean_loss, dim3(1), dim3(64), 0, stream,
                       rloss, out, n);
}